// Round 3
// baseline (1017.161 us; speedup 1.0000x reference)
//
#include <hip/hip_runtime.h>

// TriPlanePC2Encoder: scatter-mean of point features onto 3 canonical planes.
// B=8, N=200000, C=32, R=128. out[b, plane, c, row, col], plane order xy,yz,xz.
//
// Round 3: MLP-starved scatter fixed via wide loads + software pipeline.
//   scatter_kernel: per thread-iteration handles 8 points with 3 dwordx4 loads
//   (ushort8 bins + 2x float4 features), prefetching chunk i+1 before doing
//   the ds_add_f32 of chunk i. 64 KB LDS fp32 histogram per (b,plane,ch)
//   block, exclusive output ownership -> plain-store flush fused with divide.

constexpr int R     = 128;
constexpr int NBINS = R * R;        // 16384
constexpr int NPTS  = 200000;
constexpr int NB    = 8;
constexpr int NC    = 32;
constexpr int SPLIT = 16;           // point-splits in count_kernel
constexpr int CHUNKS = NPTS / 8;    // 25000 8-point chunks per slice

// ws layout: bins u16 [3][NB][NPTS]  (9,600,000 B), then cnt u32 [NB][3][NBINS]
constexpr size_t BINS_BYTES = (size_t)3 * NB * NPTS * sizeof(unsigned short);
constexpr size_t CNT_WORDS  = (size_t)NB * 3 * NBINS;

__device__ __forceinline__ int coord_bin(float p) {
    // xyz_norm = (p+1)/2 - 0.5 ; then /(1+eps) + 0.5 ; clip ; *R ; trunc
    float v = (p + 1.0f) * 0.5f - 0.5f;
    float t = v / 1.00001f + 0.5f;                     // IEEE fp32 divide
    t = fminf(fmaxf(t, 0.0f), (float)(1.0 - 1e-5));
    return (int)(t * 128.0f);
}

__global__ __launch_bounds__(256) void bin_kernel(
    const float* __restrict__ xyz, unsigned short* __restrict__ bins) {
    int i = blockIdx.x * 256 + threadIdx.x;            // over B*N
    if (i >= NB * NPTS) return;
    float x = xyz[3 * (size_t)i + 0];
    float y = xyz[3 * (size_t)i + 1];
    float z = xyz[3 * (size_t)i + 2];
    int ix = coord_bin(x), iy = coord_bin(y), iz = coord_bin(z);
    // plane dims: xy=(0,1) yz=(1,2) xz=(0,2); lin = idx_d0 + R*idx_d1
    bins[0 * (size_t)NB * NPTS + i] = (unsigned short)(ix + R * iy);
    bins[1 * (size_t)NB * NPTS + i] = (unsigned short)(iy + R * iz);
    bins[2 * (size_t)NB * NPTS + i] = (unsigned short)(ix + R * iz);
}

__global__ __launch_bounds__(1024) void count_kernel(
    const unsigned short* __restrict__ bins, unsigned* __restrict__ cnt) {
    __shared__ unsigned hist[NBINS];
    int blk   = blockIdx.x;                 // (b*3+plane)*SPLIT + split
    int split = blk & (SPLIT - 1);
    int bp    = blk / SPLIT;                // b*3 + plane
    int b     = bp / 3;
    int plane = bp - 3 * b;
    for (int i = threadIdx.x; i < NBINS; i += 1024) hist[i] = 0u;
    __syncthreads();
    const unsigned short* src = bins + ((size_t)plane * NB + b) * NPTS
                                     + (size_t)split * (NPTS / SPLIT);
    for (int n = threadIdx.x; n < NPTS / SPLIT; n += 1024)
        atomicAdd(&hist[src[n]], 1u);
    __syncthreads();
    unsigned* dst = cnt + (size_t)bp * NBINS;
    for (int i = threadIdx.x; i < NBINS; i += 1024) {
        unsigned v = hist[i];
        if (v) atomicAdd(&dst[i], v);
    }
}

__global__ __launch_bounds__(1024) void scatter_kernel(
    const unsigned short* __restrict__ bins, const float* __restrict__ feat,
    const unsigned* __restrict__ cnt, float* __restrict__ out) {
    __shared__ float hist[NBINS];           // 64 KB -> 2 blocks/CU, 32 waves/CU
    int blk   = blockIdx.x;                 // b*96 + plane*32 + ch
    int b     = blk / 96;
    int rem   = blk - b * 96;
    int plane = rem >> 5;
    int ch    = rem & 31;
    for (int i = threadIdx.x; i < NBINS; i += 1024) hist[i] = 0.0f;
    __syncthreads();

    // 8 points per chunk: bins as uint4 (8 x u16), features as 2 x float4.
    const uint4*  bp4 = (const uint4*)(bins + ((size_t)plane * NB + b) * NPTS);
    const float4* fp4 = (const float4*)(feat + ((size_t)b * NC + ch) * NPTS);

    int  p     = threadIdx.x;
    bool valid = p < CHUNKS;
    uint4 bb; float4 f0, f1;
    if (valid) { bb = bp4[p]; f0 = fp4[2 * p]; f1 = fp4[2 * p + 1]; }
    while (valid) {
        int  pn = p + 1024;
        bool vn = pn < CHUNKS;
        uint4 nbb; float4 nf0, nf1;
        if (vn) { nbb = bp4[pn]; nf0 = fp4[2 * pn]; nf1 = fp4[2 * pn + 1]; }
        // ds_add the current chunk while next chunk's loads are in flight
        atomicAdd(&hist[bb.x & 0xffffu], f0.x);
        atomicAdd(&hist[bb.x >> 16],     f0.y);
        atomicAdd(&hist[bb.y & 0xffffu], f0.z);
        atomicAdd(&hist[bb.y >> 16],     f0.w);
        atomicAdd(&hist[bb.z & 0xffffu], f1.x);
        atomicAdd(&hist[bb.z >> 16],     f1.y);
        atomicAdd(&hist[bb.w & 0xffffu], f1.z);
        atomicAdd(&hist[bb.w >> 16],     f1.w);
        bb = nbb; f0 = nf0; f1 = nf1;
        p = pn; valid = vn;
    }

    __syncthreads();
    const unsigned* cb = cnt + ((size_t)b * 3 + plane) * NBINS;
    float* ob = out + (((size_t)b * 3 + plane) * NC + ch) * (size_t)NBINS;
    for (int i = threadIdx.x; i < NBINS; i += 1024)
        ob[i] = hist[i] / fmaxf((float)cb[i], 1.0f);   // empty bins: 0/1 = 0
}

extern "C" void kernel_launch(void* const* d_in, const int* in_sizes, int n_in,
                              void* d_out, int out_size, void* d_ws, size_t ws_size,
                              hipStream_t stream) {
    const float* xyz  = (const float*)d_in[0];         // (B, N, 3)
    const float* feat = (const float*)d_in[1];         // (B, C, N)
    float* out = (float*)d_out;                        // (B, 3, C, R, R)
    unsigned short* bins = (unsigned short*)d_ws;
    unsigned* cnt = (unsigned*)((char*)d_ws + BINS_BYTES);

    hipMemsetAsync(cnt, 0, CNT_WORDS * sizeof(unsigned), stream);

    int total_pts = NB * NPTS;
    bin_kernel<<<(total_pts + 255) / 256, 256, 0, stream>>>(xyz, bins);
    count_kernel<<<NB * 3 * SPLIT, 1024, 0, stream>>>(bins, cnt);
    scatter_kernel<<<NB * 3 * NC, 1024, 0, stream>>>(bins, feat, cnt, out);
}

// Round 4
// 943.054 us; speedup vs baseline: 1.0786x; 1.0786x over previous
//
#include <hip/hip_runtime.h>

// TriPlanePC2Encoder: scatter-mean of point features onto 3 canonical planes.
// B=8, N=200000, C=32, R=128. out[b, plane, c, row, col], plane order xy,yz,xz.
//
// Round 4: counting-sort + atomic-free gather (hot loop has ZERO atomics).
//   bin -> count -> scan(offsets) -> reorder (bin-sorted point ids, LDS
//   cursors, 4.8M ds-atomics total = 32x fewer than round 3) -> transpose
//   features to point-major bf16 (one point = one 64B line) -> gather:
//   32-lane group owns 32 bins, lanes = channels, register accumulation,
//   fused divide. Fallback to the verified round-3 LDS-histogram scatter
//   if ws_size is too small for the sort buffers (~134 MB).

constexpr int R     = 128;
constexpr int NBINS = R * R;        // 16384
constexpr int NPTS  = 200000;
constexpr int NB    = 8;
constexpr int NC    = 32;
constexpr int SPLIT = 16;           // point-splits in count_kernel

// ws layout (shared prefix for both paths):
//   bins u16 [3][NB][NPTS]           @ 0          (9,600,000 B)
//   cnt  u32 [NB*3][NBINS]           @ 9,600,000  (1,572,864 B)
// fast path adds:
//   off  u32 [NB*3][NBINS]           @ 11,172,864
//   S    u32 [NB*3][NPTS]            @ 12,745,728 (19,200,000 B)
//   ftT  u16(bf16) [NB][NPTS][NC]    @ 31,945,728 (102,400,000 B)
constexpr size_t OFF_CNT = 9600000;
constexpr size_t OFF_OFF = OFF_CNT + (size_t)NB * 3 * NBINS * 4;   // 11,172,864
constexpr size_t OFF_S   = OFF_OFF + (size_t)NB * 3 * NBINS * 4;   // 12,745,728
constexpr size_t OFF_FT  = OFF_S + (size_t)NB * 3 * NPTS * 4;      // 31,945,728 (16-aligned)
constexpr size_t WS_NEED = OFF_FT + (size_t)NB * NPTS * NC * 2;    // 134,345,728

__device__ __forceinline__ int coord_bin(float p) {
    // xyz_norm = (p+1)/2 - 0.5 ; then /(1+eps) + 0.5 ; clip ; *R ; trunc
    float v = (p + 1.0f) * 0.5f - 0.5f;
    float t = v / 1.00001f + 0.5f;                     // IEEE fp32 divide
    t = fminf(fmaxf(t, 0.0f), (float)(1.0 - 1e-5));
    return (int)(t * 128.0f);
}

__global__ __launch_bounds__(256) void bin_kernel(
    const float* __restrict__ xyz, unsigned short* __restrict__ bins) {
    int i = blockIdx.x * 256 + threadIdx.x;            // over B*N
    if (i >= NB * NPTS) return;
    float x = xyz[3 * (size_t)i + 0];
    float y = xyz[3 * (size_t)i + 1];
    float z = xyz[3 * (size_t)i + 2];
    int ix = coord_bin(x), iy = coord_bin(y), iz = coord_bin(z);
    // plane dims: xy=(0,1) yz=(1,2) xz=(0,2); lin = idx_d0 + R*idx_d1
    bins[0 * (size_t)NB * NPTS + i] = (unsigned short)(ix + R * iy);
    bins[1 * (size_t)NB * NPTS + i] = (unsigned short)(iy + R * iz);
    bins[2 * (size_t)NB * NPTS + i] = (unsigned short)(ix + R * iz);
}

__global__ __launch_bounds__(1024) void count_kernel(
    const unsigned short* __restrict__ bins, unsigned* __restrict__ cnt) {
    __shared__ unsigned hist[NBINS];
    int blk   = blockIdx.x;                 // (b*3+plane)*SPLIT + split
    int split = blk & (SPLIT - 1);
    int bp    = blk / SPLIT;                // b*3 + plane
    int b     = bp / 3;
    int plane = bp - 3 * b;
    for (int i = threadIdx.x; i < NBINS; i += 1024) hist[i] = 0u;
    __syncthreads();
    const unsigned short* src = bins + ((size_t)plane * NB + b) * NPTS
                                     + (size_t)split * (NPTS / SPLIT);
    for (int n = threadIdx.x; n < NPTS / SPLIT; n += 1024)
        atomicAdd(&hist[src[n]], 1u);
    __syncthreads();
    unsigned* dst = cnt + (size_t)bp * NBINS;
    for (int i = threadIdx.x; i < NBINS; i += 1024) {
        unsigned v = hist[i];
        if (v) atomicAdd(&dst[i], v);
    }
}

// Exclusive scan of 16384 counts per (b,plane): 1024 thr x 16 elems.
__global__ __launch_bounds__(1024) void scan_kernel(
    const unsigned* __restrict__ cnt, unsigned* __restrict__ off) {
    __shared__ unsigned tsum[1024];
    int bp = blockIdx.x, t = threadIdx.x;
    const unsigned* cb = cnt + (size_t)bp * NBINS;
    unsigned* ob = off + (size_t)bp * NBINS;
    int base = t * 16;
    unsigned v[16], run = 0;
#pragma unroll
    for (int k = 0; k < 16; ++k) { unsigned x = cb[base + k]; v[k] = run; run += x; }
    tsum[t] = run;
    __syncthreads();
    for (int o = 1; o < 1024; o <<= 1) {           // Hillis-Steele inclusive
        unsigned a = (t >= o) ? tsum[t - o] : 0u;
        __syncthreads();
        tsum[t] += a;
        __syncthreads();
    }
    unsigned tb = (t > 0) ? tsum[t - 1] : 0u;
#pragma unroll
    for (int k = 0; k < 16; ++k) ob[base + k] = tb + v[k];
}

// Bin-sorted point ids per (b,plane). LDS cursors; order within bin arbitrary.
__global__ __launch_bounds__(1024) void reorder_kernel(
    const unsigned short* __restrict__ bins, const unsigned* __restrict__ off,
    unsigned* __restrict__ S) {
    __shared__ unsigned cur[NBINS];
    int bp = blockIdx.x, b = bp / 3, plane = bp - 3 * b;
    for (int i = threadIdx.x; i < NBINS; i += 1024)
        cur[i] = off[(size_t)bp * NBINS + i];
    __syncthreads();
    const unsigned short* bn = bins + ((size_t)plane * NB + b) * NPTS;
    unsigned* Sp = S + (size_t)bp * NPTS;
    for (int n = threadIdx.x; n < NPTS; n += 1024) {
        unsigned pos = atomicAdd(&cur[bn[n]], 1u);
        Sp[pos] = (unsigned)n;
    }
}

// feat (b, C, N) fp32 -> ftT (b, n, c) bf16 (RNE). One point = 64 B line.
constexpr int TTILES = (NPTS + 255) / 256;   // 782
__global__ __launch_bounds__(256) void transpose_kernel(
    const float* __restrict__ feat, unsigned short* __restrict__ ftT) {
    int b = blockIdx.x / TTILES;
    int n = (blockIdx.x % TTILES) * 256 + threadIdx.x;
    if (n >= NPTS) return;
    const float* fb = feat + (size_t)b * NC * NPTS + n;
    unsigned pk[16];
#pragma unroll
    for (int c = 0; c < 16; ++c) {
        unsigned u0 = __float_as_uint(fb[(size_t)(2 * c) * NPTS]);
        unsigned u1 = __float_as_uint(fb[(size_t)(2 * c + 1) * NPTS]);
        unsigned r0 = (u0 + 0x7fffu + ((u0 >> 16) & 1u)) >> 16;   // bf16 RNE
        unsigned r1 = (u1 + 0x7fffu + ((u1 >> 16) & 1u)) >> 16;
        pk[c] = r0 | (r1 << 16);
    }
    uint4* dst = (uint4*)(ftT + ((size_t)b * NPTS + n) * NC);
#pragma unroll
    for (int q = 0; q < 4; ++q)
        dst[q] = make_uint4(pk[4 * q], pk[4 * q + 1], pk[4 * q + 2], pk[4 * q + 3]);
}

// Atomic-free gather: 32-lane group owns 32 consecutive bins; lane = channel.
__global__ __launch_bounds__(256) void gather_kernel(
    const unsigned* __restrict__ off, const unsigned* __restrict__ S,
    const unsigned short* __restrict__ ftT, float* __restrict__ out) {
    int gid = blockIdx.x * 8 + (threadIdx.x >> 5);   // 12288 groups = 24 * 512
    int c   = threadIdx.x & 31;
    int bp  = gid >> 9;
    int gb  = (gid & 511) * 32;                      // first bin of this group
    int b   = bp / 3;
    const unsigned* op = off + (size_t)bp * NBINS;
    const unsigned* Sp = S + (size_t)bp * NPTS;
    const unsigned short* fb = ftT + (size_t)b * NPTS * NC + c;
    float* ob = out + ((size_t)bp * NC + c) * NBINS;
    unsigned s = op[gb];
    for (int i = 0; i < 32; ++i) {
        int bin = gb + i;
        unsigned e = (bin + 1 < NBINS) ? op[bin + 1] : (unsigned)NPTS;
        float acc = 0.0f;
        unsigned p = s;
        for (; p + 4 <= e; p += 4) {                 // batch S reads -> 4 lines in flight
            unsigned n0 = Sp[p], n1 = Sp[p + 1], n2 = Sp[p + 2], n3 = Sp[p + 3];
            float f0 = __uint_as_float((unsigned)fb[(size_t)n0 * NC] << 16);
            float f1 = __uint_as_float((unsigned)fb[(size_t)n1 * NC] << 16);
            float f2 = __uint_as_float((unsigned)fb[(size_t)n2 * NC] << 16);
            float f3 = __uint_as_float((unsigned)fb[(size_t)n3 * NC] << 16);
            acc += (f0 + f1) + (f2 + f3);
        }
        for (; p < e; ++p)
            acc += __uint_as_float((unsigned)fb[(size_t)Sp[p] * NC] << 16);
        ob[bin] = acc / fmaxf((float)(e - s), 1.0f); // empty bins: 0/1 = 0
        s = e;
    }
}

// ---------- fallback (round-3 verified path) ----------
constexpr int CHUNKS = NPTS / 8;
__global__ __launch_bounds__(1024) void scatter_kernel(
    const unsigned short* __restrict__ bins, const float* __restrict__ feat,
    const unsigned* __restrict__ cnt, float* __restrict__ out) {
    __shared__ float hist[NBINS];
    int blk   = blockIdx.x;                 // b*96 + plane*32 + ch
    int b     = blk / 96;
    int rem   = blk - b * 96;
    int plane = rem >> 5;
    int ch    = rem & 31;
    for (int i = threadIdx.x; i < NBINS; i += 1024) hist[i] = 0.0f;
    __syncthreads();
    const uint4*  bp4 = (const uint4*)(bins + ((size_t)plane * NB + b) * NPTS);
    const float4* fp4 = (const float4*)(feat + ((size_t)b * NC + ch) * NPTS);
    for (int p = threadIdx.x; p < CHUNKS; p += 1024) {
        uint4 bb = bp4[p];
        float4 f0 = fp4[2 * p], f1 = fp4[2 * p + 1];
        atomicAdd(&hist[bb.x & 0xffffu], f0.x);
        atomicAdd(&hist[bb.x >> 16],     f0.y);
        atomicAdd(&hist[bb.y & 0xffffu], f0.z);
        atomicAdd(&hist[bb.y >> 16],     f0.w);
        atomicAdd(&hist[bb.z & 0xffffu], f1.x);
        atomicAdd(&hist[bb.z >> 16],     f1.y);
        atomicAdd(&hist[bb.w & 0xffffu], f1.z);
        atomicAdd(&hist[bb.w >> 16],     f1.w);
    }
    __syncthreads();
    const unsigned* cb = cnt + ((size_t)b * 3 + plane) * NBINS;
    float* ob = out + (((size_t)b * 3 + plane) * NC + ch) * (size_t)NBINS;
    for (int i = threadIdx.x; i < NBINS; i += 1024)
        ob[i] = hist[i] / fmaxf((float)cb[i], 1.0f);
}

extern "C" void kernel_launch(void* const* d_in, const int* in_sizes, int n_in,
                              void* d_out, int out_size, void* d_ws, size_t ws_size,
                              hipStream_t stream) {
    const float* xyz  = (const float*)d_in[0];         // (B, N, 3)
    const float* feat = (const float*)d_in[1];         // (B, C, N)
    float* out = (float*)d_out;                        // (B, 3, C, R, R)
    unsigned short* bins = (unsigned short*)d_ws;
    unsigned* cnt = (unsigned*)((char*)d_ws + OFF_CNT);

    hipMemsetAsync(cnt, 0, (size_t)NB * 3 * NBINS * sizeof(unsigned), stream);

    int total_pts = NB * NPTS;
    bin_kernel<<<(total_pts + 255) / 256, 256, 0, stream>>>(xyz, bins);
    count_kernel<<<NB * 3 * SPLIT, 1024, 0, stream>>>(bins, cnt);

    if (ws_size >= WS_NEED) {
        unsigned* off = (unsigned*)((char*)d_ws + OFF_OFF);
        unsigned* S   = (unsigned*)((char*)d_ws + OFF_S);
        unsigned short* ftT = (unsigned short*)((char*)d_ws + OFF_FT);
        transpose_kernel<<<NB * TTILES, 256, 0, stream>>>(feat, ftT);
        scan_kernel<<<NB * 3, 1024, 0, stream>>>(cnt, off);
        reorder_kernel<<<NB * 3, 1024, 0, stream>>>(bins, off, S);
        gather_kernel<<<NB * 3 * 512 / 8, 256, 0, stream>>>(off, S, ftT, out);
    } else {
        scatter_kernel<<<NB * 3 * NC, 1024, 0, stream>>>(bins, feat, cnt, out);
    }
}

// Round 5
// 606.137 us; speedup vs baseline: 1.6781x; 1.5558x over previous
//
#include <hip/hip_runtime.h>

// TriPlanePC2Encoder: scatter-mean of point features onto 3 canonical planes.
// B=8, N=200000, C=32, R=128. out[b, plane, c, row, col], plane order xy,yz,xz.
//
// Round 5: counting-sort pipeline, all stages parallel; atomic-free gather
// with register accumulation and full-line coalesced writes.
//   bin -> count (per-split u16 hists, 384 blocks) -> scan (per-split
//   offsets, parallel over bins) -> reorder (384 blocks, LDS cursors) ->
//   transpose (feat -> point-major bf16) -> gather (32-lane group = 32
//   contiguous bins, lane = channel, float4 stores).
// ws overlay: bins/cntS/offS (first ~47MB) are dead before transpose runs,
// so ftT (102.4MB) overlays them. WS_NEED = 123.2MB (<134MB proven in R4).

constexpr int R     = 128;
constexpr int NBINS = R * R;        // 16384
constexpr int NPTS  = 200000;
constexpr int NB    = 8;
constexpr int NC    = 32;
constexpr int SPLIT = 16;           // sort tiles per (b,plane)
constexpr int TILE  = NPTS / SPLIT; // 12500 (fits u16 counts)

// ws layout:
//  phase1 (dead after reorder, overlaid by ftT later):
//    bins u16 [3][NB][NPTS]        @ 0           (9,600,000)
//    cntS u16 [24][SPLIT][NBINS]   @ 9,600,000   (12,582,912)
//    offS u32 [24][SPLIT][NBINS]   @ 22,182,912  (25,165,824)  end 47,348,736
//  phase2: ftT bf16 [NB][NPTS][NC] @ 0           (102,400,000)
//  persistent tail:
//    off  u32 [24][NBINS]          @ 102,400,000 (1,572,864)
//    S    u32 [24][NPTS]           @ 103,972,864 (19,200,000)  end 123,172,864
constexpr size_t OFF_CNTS = 9600000;
constexpr size_t OFF_OFFS = 22182912;
constexpr size_t OFF_OFF  = 102400000;
constexpr size_t OFF_S    = 103972864;
constexpr size_t WS_NEED  = 123172864;

__device__ __forceinline__ int coord_bin(float p) {
    // xyz_norm = (p+1)/2 - 0.5 ; then /(1+eps) + 0.5 ; clip ; *R ; trunc
    float v = (p + 1.0f) * 0.5f - 0.5f;
    float t = v / 1.00001f + 0.5f;                     // IEEE fp32 divide
    t = fminf(fmaxf(t, 0.0f), (float)(1.0 - 1e-5));
    return (int)(t * 128.0f);
}

__global__ __launch_bounds__(256) void bin_kernel(
    const float* __restrict__ xyz, unsigned short* __restrict__ bins) {
    int i = blockIdx.x * 256 + threadIdx.x;            // over B*N
    if (i >= NB * NPTS) return;
    float x = xyz[3 * (size_t)i + 0];
    float y = xyz[3 * (size_t)i + 1];
    float z = xyz[3 * (size_t)i + 2];
    int ix = coord_bin(x), iy = coord_bin(y), iz = coord_bin(z);
    // plane dims: xy=(0,1) yz=(1,2) xz=(0,2); lin = idx_d0 + R*idx_d1
    bins[0 * (size_t)NB * NPTS + i] = (unsigned short)(ix + R * iy);
    bins[1 * (size_t)NB * NPTS + i] = (unsigned short)(iy + R * iz);
    bins[2 * (size_t)NB * NPTS + i] = (unsigned short)(ix + R * iz);
}

// Per-(bp,split) u16 histogram. blk = bp*SPLIT + split.
__global__ __launch_bounds__(1024) void count_kernel(
    const unsigned short* __restrict__ bins, unsigned short* __restrict__ cntS) {
    __shared__ unsigned hist[NBINS];
    int blk   = blockIdx.x;
    int split = blk & (SPLIT - 1);
    int bp    = blk >> 4;
    int b     = bp / 3, plane = bp - 3 * b;
    for (int i = threadIdx.x; i < NBINS; i += 1024) hist[i] = 0u;
    __syncthreads();
    const unsigned* src = (const unsigned*)(bins + ((size_t)plane * NB + b) * NPTS
                                                 + (size_t)split * TILE);
    for (int j = threadIdx.x; j < TILE / 2; j += 1024) {
        unsigned u = src[j];
        atomicAdd(&hist[u & 0xffffu], 1u);
        atomicAdd(&hist[u >> 16], 1u);
    }
    __syncthreads();
    unsigned short* dst = cntS + (size_t)blk * NBINS;
    for (int i = threadIdx.x; i < NBINS; i += 1024)
        dst[i] = (unsigned short)hist[i];
}

// Per-bp: cross-split + cross-bin exclusive scan. Writes per-split offsets
// (reorder) and per-bin base offsets (gather). 24 blocks x 1024 thr x 16 bins.
__global__ __launch_bounds__(1024) void scan_kernel(
    const unsigned short* __restrict__ cntS, unsigned* __restrict__ off,
    unsigned* __restrict__ offS) {
    __shared__ unsigned tsum[1024];
    int bp = blockIdx.x, t = threadIdx.x;
    const unsigned short* cb = cntS + (size_t)bp * SPLIT * NBINS;
    int base = t * 16;
    unsigned tot[16], v[16];
#pragma unroll
    for (int k = 0; k < 16; ++k) {
        unsigned r = 0;
        for (int s = 0; s < SPLIT; ++s) r += cb[(size_t)s * NBINS + base + k];
        tot[k] = r;
    }
    unsigned run = 0;
#pragma unroll
    for (int k = 0; k < 16; ++k) { v[k] = run; run += tot[k]; }
    tsum[t] = run;
    __syncthreads();
    for (int o = 1; o < 1024; o <<= 1) {           // Hillis-Steele inclusive
        unsigned a = (t >= o) ? tsum[t - o] : 0u;
        __syncthreads();
        tsum[t] += a;
        __syncthreads();
    }
    unsigned tb = (t > 0) ? tsum[t - 1] : 0u;
    unsigned* ob  = off  + (size_t)bp * NBINS;
    unsigned* osb = offS + (size_t)bp * SPLIT * NBINS;
#pragma unroll
    for (int k = 0; k < 16; ++k) {
        unsigned bb = tb + v[k];
        ob[base + k] = bb;
        unsigned r = 0;
        for (int s = 0; s < SPLIT; ++s) {
            osb[(size_t)s * NBINS + base + k] = bb + r;
            r += cb[(size_t)s * NBINS + base + k];
        }
    }
}

// Bin-sorted point ids; 384 independent blocks via per-split offsets.
__global__ __launch_bounds__(1024) void reorder_kernel(
    const unsigned short* __restrict__ bins, const unsigned* __restrict__ offS,
    unsigned* __restrict__ S) {
    __shared__ unsigned cur[NBINS];
    int blk   = blockIdx.x;
    int split = blk & (SPLIT - 1);
    int bp    = blk >> 4;
    int b     = bp / 3, plane = bp - 3 * b;
    const unsigned* osb = offS + (size_t)blk * NBINS;
    for (int i = threadIdx.x; i < NBINS; i += 1024) cur[i] = osb[i];
    __syncthreads();
    const unsigned* src = (const unsigned*)(bins + ((size_t)plane * NB + b) * NPTS
                                                 + (size_t)split * TILE);
    unsigned nbase = (unsigned)(split * TILE);
    unsigned* Sp = S + (size_t)bp * NPTS;
    for (int j = threadIdx.x; j < TILE / 2; j += 1024) {
        unsigned u  = src[j];
        unsigned p0 = atomicAdd(&cur[u & 0xffffu], 1u);
        Sp[p0] = nbase + 2 * j;
        unsigned p1 = atomicAdd(&cur[u >> 16], 1u);
        Sp[p1] = nbase + 2 * j + 1;
    }
}

// feat (b, C, N) fp32 -> ftT (b, n, c) bf16 (RNE). One point = 64 B line.
constexpr int TTILES = (NPTS + 255) / 256;   // 782
__global__ __launch_bounds__(256) void transpose_kernel(
    const float* __restrict__ feat, unsigned short* __restrict__ ftT) {
    int b = blockIdx.x / TTILES;
    int n = (blockIdx.x % TTILES) * 256 + threadIdx.x;
    if (n >= NPTS) return;
    const float* fb = feat + (size_t)b * NC * NPTS + n;
    unsigned pk[16];
#pragma unroll
    for (int c = 0; c < 16; ++c) {
        unsigned u0 = __float_as_uint(fb[(size_t)(2 * c) * NPTS]);
        unsigned u1 = __float_as_uint(fb[(size_t)(2 * c + 1) * NPTS]);
        unsigned r0 = (u0 + 0x7fffu + ((u0 >> 16) & 1u)) >> 16;   // bf16 RNE
        unsigned r1 = (u1 + 0x7fffu + ((u1 >> 16) & 1u)) >> 16;
        pk[c] = r0 | (r1 << 16);
    }
    uint4* dst = (uint4*)(ftT + ((size_t)b * NPTS + n) * NC);
#pragma unroll
    for (int q = 0; q < 4; ++q)
        dst[q] = make_uint4(pk[4 * q], pk[4 * q + 1], pk[4 * q + 2], pk[4 * q + 3]);
}

__device__ __forceinline__ float bf2f(unsigned short h) {
    return __uint_as_float((unsigned)h << 16);
}

// Atomic-free gather: 32-lane group owns 32 contiguous bins; lane = channel.
// Register accumulation per 4 bins -> float4 stores (full-line coalescing).
__global__ __launch_bounds__(256) void gather_kernel(
    const unsigned* __restrict__ off, const unsigned* __restrict__ S,
    const unsigned short* __restrict__ ftT, float* __restrict__ out) {
    int g   = threadIdx.x >> 5, c = threadIdx.x & 31;
    int gid = blockIdx.x * 8 + g;                    // 12288 = 24 * 512
    int bp  = gid >> 9;
    int gb  = (gid & 511) * 32;                      // first bin of this group
    int b   = bp / 3;
    const unsigned* op = off + (size_t)bp * NBINS;
    unsigned myoff  = op[gb + c];                    // lane c -> offset of bin gb+c
    unsigned endoff = (gb + 32 < NBINS) ? op[gb + 32] : (unsigned)NPTS;
    const unsigned* Sp = S + (size_t)bp * NPTS;
    const unsigned short* fb = ftT + (size_t)b * NPTS * NC + c;
    float4* ob4 = (float4*)(out + ((size_t)bp * NC + c) * NBINS + gb);

    unsigned s = __shfl(myoff, 0, 32);
    for (int q = 0; q < 8; ++q) {
        float a4[4];
#pragma unroll
        for (int i = 0; i < 4; ++i) {
            int bin_i  = 4 * q + i;
            unsigned e = (bin_i < 31) ? __shfl(myoff, bin_i + 1, 32) : endoff;
            float acc = 0.0f;
            unsigned p = s;
            for (; p + 8 <= e; p += 8) {
                unsigned n0 = Sp[p],     n1 = Sp[p + 1], n2 = Sp[p + 2], n3 = Sp[p + 3];
                unsigned n4 = Sp[p + 4], n5 = Sp[p + 5], n6 = Sp[p + 6], n7 = Sp[p + 7];
                float f0 = bf2f(fb[(size_t)n0 * NC]), f1 = bf2f(fb[(size_t)n1 * NC]);
                float f2 = bf2f(fb[(size_t)n2 * NC]), f3 = bf2f(fb[(size_t)n3 * NC]);
                float f4 = bf2f(fb[(size_t)n4 * NC]), f5 = bf2f(fb[(size_t)n5 * NC]);
                float f6 = bf2f(fb[(size_t)n6 * NC]), f7 = bf2f(fb[(size_t)n7 * NC]);
                acc += ((f0 + f1) + (f2 + f3)) + ((f4 + f5) + (f6 + f7));
            }
            for (; p + 4 <= e; p += 4) {
                unsigned n0 = Sp[p], n1 = Sp[p + 1], n2 = Sp[p + 2], n3 = Sp[p + 3];
                float f0 = bf2f(fb[(size_t)n0 * NC]), f1 = bf2f(fb[(size_t)n1 * NC]);
                float f2 = bf2f(fb[(size_t)n2 * NC]), f3 = bf2f(fb[(size_t)n3 * NC]);
                acc += (f0 + f1) + (f2 + f3);
            }
            for (; p < e; ++p) acc += bf2f(fb[(size_t)Sp[p] * NC]);
            a4[i] = acc / fmaxf((float)(e - s), 1.0f);   // empty bins: 0/1 = 0
            s = e;
        }
        ob4[q] = make_float4(a4[0], a4[1], a4[2], a4[3]);
    }
}

// ---------- fallback (round-3 verified path; needs only bins + cnt) ----------
constexpr int CHUNKS = NPTS / 8;
__global__ __launch_bounds__(1024) void count_fb_kernel(
    const unsigned short* __restrict__ bins, unsigned* __restrict__ cnt) {
    __shared__ unsigned hist[NBINS];
    int blk   = blockIdx.x;
    int split = blk & (SPLIT - 1);
    int bp    = blk >> 4;
    int b     = bp / 3, plane = bp - 3 * b;
    for (int i = threadIdx.x; i < NBINS; i += 1024) hist[i] = 0u;
    __syncthreads();
    const unsigned short* src = bins + ((size_t)plane * NB + b) * NPTS
                                     + (size_t)split * TILE;
    for (int n = threadIdx.x; n < TILE; n += 1024) atomicAdd(&hist[src[n]], 1u);
    __syncthreads();
    unsigned* dst = cnt + (size_t)bp * NBINS;
    for (int i = threadIdx.x; i < NBINS; i += 1024) {
        unsigned v = hist[i];
        if (v) atomicAdd(&dst[i], v);
    }
}
__global__ __launch_bounds__(1024) void scatter_kernel(
    const unsigned short* __restrict__ bins, const float* __restrict__ feat,
    const unsigned* __restrict__ cnt, float* __restrict__ out) {
    __shared__ float hist[NBINS];
    int blk = blockIdx.x, b = blk / 96;
    int rem = blk - b * 96, plane = rem >> 5, ch = rem & 31;
    for (int i = threadIdx.x; i < NBINS; i += 1024) hist[i] = 0.0f;
    __syncthreads();
    const uint4*  bp4 = (const uint4*)(bins + ((size_t)plane * NB + b) * NPTS);
    const float4* fp4 = (const float4*)(feat + ((size_t)b * NC + ch) * NPTS);
    for (int p = threadIdx.x; p < CHUNKS; p += 1024) {
        uint4 bb = bp4[p];
        float4 f0 = fp4[2 * p], f1 = fp4[2 * p + 1];
        atomicAdd(&hist[bb.x & 0xffffu], f0.x);
        atomicAdd(&hist[bb.x >> 16],     f0.y);
        atomicAdd(&hist[bb.y & 0xffffu], f0.z);
        atomicAdd(&hist[bb.y >> 16],     f0.w);
        atomicAdd(&hist[bb.z & 0xffffu], f1.x);
        atomicAdd(&hist[bb.z >> 16],     f1.y);
        atomicAdd(&hist[bb.w & 0xffffu], f1.z);
        atomicAdd(&hist[bb.w >> 16],     f1.w);
    }
    __syncthreads();
    const unsigned* cb = cnt + (size_t)(b * 3 + plane) * NBINS;
    float* ob = out + (((size_t)b * 3 + plane) * NC + ch) * (size_t)NBINS;
    for (int i = threadIdx.x; i < NBINS; i += 1024)
        ob[i] = hist[i] / fmaxf((float)cb[i], 1.0f);
}

extern "C" void kernel_launch(void* const* d_in, const int* in_sizes, int n_in,
                              void* d_out, int out_size, void* d_ws, size_t ws_size,
                              hipStream_t stream) {
    const float* xyz  = (const float*)d_in[0];         // (B, N, 3)
    const float* feat = (const float*)d_in[1];         // (B, C, N)
    float* out = (float*)d_out;                        // (B, 3, C, R, R)
    char* ws = (char*)d_ws;
    unsigned short* bins = (unsigned short*)ws;

    int total_pts = NB * NPTS;
    bin_kernel<<<(total_pts + 255) / 256, 256, 0, stream>>>(xyz, bins);

    if (ws_size >= WS_NEED) {
        unsigned short* cntS = (unsigned short*)(ws + OFF_CNTS);
        unsigned* offS = (unsigned*)(ws + OFF_OFFS);
        unsigned* off  = (unsigned*)(ws + OFF_OFF);
        unsigned* S    = (unsigned*)(ws + OFF_S);
        unsigned short* ftT = (unsigned short*)ws;     // overlays phase-1 bufs
        count_kernel<<<NB * 3 * SPLIT, 1024, 0, stream>>>(bins, cntS);
        scan_kernel<<<NB * 3, 1024, 0, stream>>>(cntS, off, offS);
        reorder_kernel<<<NB * 3 * SPLIT, 1024, 0, stream>>>(bins, offS, S);
        transpose_kernel<<<NB * TTILES, 256, 0, stream>>>(feat, ftT);  // after reorder!
        gather_kernel<<<NB * 3 * 512 / 8, 256, 0, stream>>>(off, S, ftT, out);
    } else {
        unsigned* cnt = (unsigned*)(ws + OFF_CNTS);
        hipMemsetAsync(cnt, 0, (size_t)NB * 3 * NBINS * sizeof(unsigned), stream);
        count_fb_kernel<<<NB * 3 * SPLIT, 1024, 0, stream>>>(bins, cnt);
        scatter_kernel<<<NB * 3 * NC, 1024, 0, stream>>>(bins, feat, cnt, out);
    }
}